// Round 5
// baseline (359.778 us; speedup 1.0000x reference)
//
#include <hip/hip_runtime.h>
#include <hip/hip_bf16.h>

// RowAttention, MFMA version (bf16 MFMA, fp32 acc). Inputs fp32, output fp32.
// v6 = v5 + __launch_bounds__(1024, 4).
//   v4/v5 spilled xv[32] to scratch (+135MB WRITE, +110MB FETCH, VGPR=64):
//   the allocator targeted 8 waves/SIMD (64-VGPR bin) although LDS=160KB caps
//   the CU at ONE 16-wave block = 4 waves/SIMD. Declaring min-waves/EU=4 sets
//   the allocator target to the real occupancy -> 128-VGPR budget, no spill.
//   Also: epilogue residual now 2x ds_read_b64 + unpack (was 8x ds_read_u16).
// grid=256 (1 block/CU), block=1024 (16 waves, 4/SIMD). Wave grid 4x4:
// mi=wid>>2 owns a 16-row m-slice, nj=wid&3 owns a 32-wide w-window.
//
// Counted-vmcnt gate discipline (per-wave, in-order retirement):
//   issue order is pinned with sched_barrier(0) after each VMEM group.
//   gate N = (# VMEM instrs this wave issued AFTER the staging group it
//   must wait for). Stores count in vmcnt (8 per mc epilogue).
//     P0-end:  vmcnt(8)  [newer: 8 prev-mc3 stores; pair01 staged mc3-mid]
//     P1 kc2:  vmcnt(2)  [newer: pair3 stage (2)]
//     P1 kc3:  vmcnt(0)
//     mc0-top: vmcnt(0)  [wv(mc0) staged at P2-top, nothing newer]
//     mc1/2:   vmcnt(8)  [newer: 8 stores]
//     mc3-top: vmcnt(40) r<3 [newer: 32 x-loads + 8 stores], else vmcnt(8)
//   x burst for row r+1 is issued at mc2-mid AFTER the wv(mc3) stage, so no
//   gate targets anything newer than x until x is consumed at next P0.
//
// LDS map (bytes):
//   [0,     67584)  Xt  [128 w][264 c] bf16                       (whole row)
//   [67584,104448)  Qt[128][72]+Kt[128][72] bf16 -> Pl [128][136] bf16 (P3+)
//   [104448,141312) W pages: P1 = 2x18432 slots; P4 = 36864 per-mc wv chunk
//   [141312,158720) Vl  [64 c][136 v] bf16  (first 4 KB = softmax partials)
//   [158720,160256) biases fp32: bq[64] bk[64] bv[256]

typedef short bf16x8 __attribute__((ext_vector_type(8)));
typedef float f32x4 __attribute__((ext_vector_type(4)));
using u32 = unsigned int;
using u16 = unsigned short;

#define XT_OFF   0
#define XT_SB    528
#define QT_OFF   67584
#define KT_OFF   86016
#define QK_SB    144
#define PL_OFF   67584
#define PL_SB    272
#define WP_OFF   104448
#define VL_OFF   141312
#define VL_SB    272
#define SMP_OFF  141312
#define BIAS_OFF 158720
#define LDS_TOTAL 160256

// workspace: wqk_p [4 kc][2 sel(wq,wk)][64][72] bf16 (73728 B) then
//            wv_p  [4 mc][4 kc][64][72] bf16 (147456 B)
#define WS_WQK   0
#define WS_WV    73728

__device__ __forceinline__ u16 bfbits(float f) {
    __hip_bfloat16 h = __float2bfloat16(f);
    u16 u; __builtin_memcpy(&u, &h, 2); return u;
}
__device__ __forceinline__ u32 packbf2(float a, float b) {
    return (u32)bfbits(a) | ((u32)bfbits(b) << 16);
}
__device__ __forceinline__ float bf2f(u16 u) {
    union { u32 i; float f; } v; v.i = ((u32)u) << 16; return v.f;
}

// async global->LDS 16B copy; LDS dest is wave-uniform base + lane*16.
__device__ __forceinline__ void gl2lds16(const char* g, const char* l) {
    __builtin_amdgcn_global_load_lds(
        (const __attribute__((address_space(1))) void*)(unsigned long long)g,
        (__attribute__((address_space(3))) void*)(u32)(unsigned long long)l,
        16, 0, 0);
}
// stage 18432 B over 16 waves: exactly 2 vm instrs per wave (2nd lane-masked)
__device__ __forceinline__ void stage18k(const char* g, const char* lds, int w, int l) {
    gl2lds16(g + w * 1024 + l * 16, lds + w * 1024);
    if (l < 8) gl2lds16(g + 16384 + w * 128 + l * 16, lds + 16384 + w * 128);
}
// stage 36864 B over 16 waves: exactly 3 vm instrs per wave
__device__ __forceinline__ void stage36k(const char* g, const char* lds, int w, int l) {
    gl2lds16(g + w * 1024 + l * 16,         lds + w * 1024);
    gl2lds16(g + 16384 + w * 1024 + l * 16, lds + 16384 + w * 1024);
    if (l < 16) gl2lds16(g + 32768 + w * 256 + l * 16, lds + 32768 + w * 256);
}

#define GATE(WAITSTR) do { \
    __builtin_amdgcn_sched_barrier(0); \
    asm volatile(WAITSTR "\n\ts_barrier" ::: "memory"); \
    __builtin_amdgcn_sched_barrier(0); \
} while (0)

// plain barrier: per-wave lgkm already drained by operand consumption
__device__ __forceinline__ void hard_barrier() {
    __builtin_amdgcn_sched_barrier(0);
    asm volatile("s_barrier" ::: "memory");
    __builtin_amdgcn_sched_barrier(0);
}
__device__ __forceinline__ void lgkm_barrier() {
    __builtin_amdgcn_sched_barrier(0);
    asm volatile("s_waitcnt lgkmcnt(0)\n\ts_barrier" ::: "memory");
    __builtin_amdgcn_sched_barrier(0);
}
__device__ __forceinline__ void pin() { __builtin_amdgcn_sched_barrier(0); }

__global__ void prep_weights(const float* __restrict__ wq, const float* __restrict__ wk,
                             const float* __restrict__ wv, u32* __restrict__ ws) {
    int i = blockIdx.x * 256 + threadIdx.x;        // u32 word index, 55296 total
    if (i >= 55296) return;
    u32 v = 0;
    if (i < 18432) {                               // wqk_p: 8 chunk-halves of 2304 words
        int c = i / 2304, rem = i % 2304;
        int row = rem / 36, iw = rem % 36;
        int kc = c >> 1;
        const float* m = (c & 1) ? wk : wq;
        if (iw < 32) {
            int col = kc * 64 + iw * 2;
            v = packbf2(m[row * 256 + col], m[row * 256 + col + 1]);
        }
    } else {                                       // wv_p: 16 chunks of 2304 words
        int j = i - 18432;
        int c = j / 2304, rem = j % 2304;
        int row = rem / 36, iw = rem % 36;
        int mc = c >> 2, kc = c & 3;
        if (iw < 32) {
            int col = kc * 64 + iw * 2;
            v = packbf2(wv[(mc * 64 + row) * 256 + col], wv[(mc * 64 + row) * 256 + col + 1]);
        }
    }
    ws[i] = v;
}

__global__ __launch_bounds__(1024, 4) void rowattn_mfma(
    const float* __restrict__ x,      // (8,256,128,128)
    const float* __restrict__ bq,     // (64,)
    const float* __restrict__ bk,     // (64,)
    const float* __restrict__ bv,     // (256,)
    const float* __restrict__ gamma,  // (1,)
    const char* __restrict__ wsp,     // prep_weights output (bf16, padded chunks)
    float* __restrict__ out)          // (8,256,128,128)
{
    __shared__ __align__(16) char smem[LDS_TOTAL];
    const int t  = threadIdx.x;                             // 0..1023
    const int l  = t & 63;
    const int a  = l & 15;                                  // MFMA col-within-tile
    const int q  = l >> 4;                                  // MFMA quad
    const int wid = __builtin_amdgcn_readfirstlane(t >> 6); // 0..15
    const int mi = wid >> 2;                                // m-slice 0..3
    const int nj = wid & 3;                                 // n-window 0..3
    const int w0 = nj * 32;                                 // w-window base

    const int blk = blockIdx.x;                             // 0..255
    const int b   = blk >> 5;
    const int h0  = (blk & 31) * 4;                         // 4 consecutive h rows

    const char* wqk_g = wsp + WS_WQK;
    const char* wv_g  = wsp + WS_WV;
    const float g = gamma[0];

    // ---- entry: pair0/1 DMA first (oldest), then bias, then row-0 x burst ----
    stage18k(wqk_g,         smem + WP_OFF,         wid, l);
    stage18k(wqk_g + 18432, smem + WP_OFF + 18432, wid, l);
    pin();

    float* biasl = (float*)(smem + BIAS_OFF);
    if (t < 384) {
        float v;
        if (t < 64) v = bq[t];
        else if (t < 128) v = bk[t - 64];
        else v = bv[t - 128];
        biasl[t] = v;
    }

    const int xw  = ((wid & 8) << 3) + l;                   // 0..127
    const int xcb = (wid & 7) * 4;                          // c base 0..28
    const float* xbase = x + (size_t)(b * 256 + xcb) * 16384 + xw;
    float xv[32];
    {
        const float* xp = xbase + h0 * 128;
#pragma unroll
        for (int p = 0; p < 8; ++p)
#pragma unroll
            for (int j = 0; j < 4; ++j)
                xv[p * 4 + j] = xp[(p * 32 + j) * 16384];
    }
    pin();

#pragma unroll 1
    for (int r = 0; r < 4; ++r) {
        const int h = h0 + r;
        if (r) lgkm_barrier();              // prev row epilogue Xt reads done

        // ---- P0: pack xv -> Xt[w][c] (consumes x => all older VMEM retired) ----
#pragma unroll
        for (int p = 0; p < 8; ++p) {
            uint2 pk;
            pk.x = packbf2(xv[p * 4 + 0], xv[p * 4 + 1]);
            pk.y = packbf2(xv[p * 4 + 2], xv[p * 4 + 3]);
            *(uint2*)(smem + XT_OFF + xw * XT_SB + (xcb + p * 32) * 2) = pk;
        }
        // Xt visible + pair0/1 pages done (newer-than-pair01 = 8 prev stores)
        GATE("s_waitcnt vmcnt(8) lgkmcnt(0)");

        // ---- P1: Q,K projections -> Qt[wq][o], Kt[wk][o] ----
        f32x4 accQ[2], accK[2];
        {
            f32x4 cq, ck;
#pragma unroll
            for (int rr = 0; rr < 4; ++rr) {
                cq[rr] = biasl[mi * 16 + q * 4 + rr];
                ck[rr] = biasl[64 + mi * 16 + q * 4 + rr];
            }
            accQ[0] = cq; accQ[1] = cq; accK[0] = ck; accK[1] = ck;
        }
#pragma unroll
        for (int kc = 0; kc < 4; ++kc) {
            if (kc == 2) GATE("s_waitcnt vmcnt(2)");   // pair2 done (pair3's 2 fly)
            if (kc == 3) GATE("s_waitcnt vmcnt(0)");   // pair3 done
            const char* wqp = smem + WP_OFF + (kc & 1) * 18432;
            const char* wkp = wqp + 9216;
#pragma unroll
            for (int ks = 0; ks < 2; ++ks) {
                bf16x8 aq = *(const bf16x8*)(wqp + (mi * 16 + a) * 144 + ks * 64 + q * 16);
                bf16x8 ak = *(const bf16x8*)(wkp + (mi * 16 + a) * 144 + ks * 64 + q * 16);
#pragma unroll
                for (int nt = 0; nt < 2; ++nt) {
                    bf16x8 bx = *(const bf16x8*)(smem + XT_OFF + (w0 + nt * 16 + a) * XT_SB + (kc * 64 + ks * 32) * 2 + q * 16);
                    accQ[nt] = __builtin_amdgcn_mfma_f32_16x16x32_bf16(aq, bx, accQ[nt], 0, 0, 0);
                    accK[nt] = __builtin_amdgcn_mfma_f32_16x16x32_bf16(ak, bx, accK[nt], 0, 0, 0);
                }
            }
            if (kc == 0) { hard_barrier(); stage18k(wqk_g + 2 * 18432, smem + WP_OFF,         wid, l); pin(); }
            if (kc == 1) { hard_barrier(); stage18k(wqk_g + 3 * 18432, smem + WP_OFF + 18432, wid, l); pin(); }
        }
        // write Qt/Kt transposed: C[m=o][n=w] -> Qt[w][o]
#pragma unroll
        for (int nt = 0; nt < 2; ++nt) {
            const int wrow = w0 + nt * 16 + a;
            uint2 pq; pq.x = packbf2(accQ[nt][0], accQ[nt][1]); pq.y = packbf2(accQ[nt][2], accQ[nt][3]);
            *(uint2*)(smem + QT_OFF + wrow * QK_SB + (mi * 16 + q * 4) * 2) = pq;
            uint2 pk; pk.x = packbf2(accK[nt][0], accK[nt][1]); pk.y = packbf2(accK[nt][2], accK[nt][3]);
            *(uint2*)(smem + KT_OFF + wrow * QK_SB + (mi * 16 + q * 4) * 2) = pk;
        }
        GATE("s_waitcnt lgkmcnt(0)");       // Qt/Kt visible; kc3 page reads done
        stage36k(wv_g, smem + WP_OFF, wid, l);  // wv mc0 (hidden under P2/P3)
        pin();

        // ---- P2: St tiles; wave (mi,nj): wk in [mi*32,+32), wq in [nj*32,+32) ----
        f32x4 st[2][2];
#pragma unroll
        for (int mt2 = 0; mt2 < 2; ++mt2)
#pragma unroll
            for (int nt = 0; nt < 2; ++nt) st[mt2][nt] = (f32x4){0.f, 0.f, 0.f, 0.f};
#pragma unroll
        for (int ks = 0; ks < 2; ++ks) {
            bf16x8 bq0 = *(const bf16x8*)(smem + QT_OFF + (w0 + a) * QK_SB + ks * 64 + q * 16);
            bf16x8 bq1 = *(const bf16x8*)(smem + QT_OFF + (w0 + 16 + a) * QK_SB + ks * 64 + q * 16);
            bf16x8 ak0 = *(const bf16x8*)(smem + KT_OFF + (mi * 32 + a) * QK_SB + ks * 64 + q * 16);
            bf16x8 ak1 = *(const bf16x8*)(smem + KT_OFF + (mi * 32 + 16 + a) * QK_SB + ks * 64 + q * 16);
            st[0][0] = __builtin_amdgcn_mfma_f32_16x16x32_bf16(ak0, bq0, st[0][0], 0, 0, 0);
            st[0][1] = __builtin_amdgcn_mfma_f32_16x16x32_bf16(ak0, bq1, st[0][1], 0, 0, 0);
            st[1][0] = __builtin_amdgcn_mfma_f32_16x16x32_bf16(ak1, bq0, st[1][0], 0, 0, 0);
            st[1][1] = __builtin_amdgcn_mfma_f32_16x16x32_bf16(ak1, bq1, st[1][1], 0, 0, 0);
        }
        // ---- P3: softmax: in-wave partial (32 wk) then 4-way mi-combine ----
        {
            float pmax[2], psum[2];
#pragma unroll
            for (int nt = 0; nt < 2; ++nt) {
                float mx = -3.0e38f;
#pragma unroll
                for (int mt2 = 0; mt2 < 2; ++mt2)
#pragma unroll
                    for (int rr = 0; rr < 4; ++rr) mx = fmaxf(mx, st[mt2][nt][rr]);
                mx = fmaxf(mx, __shfl_xor(mx, 16, 64));
                mx = fmaxf(mx, __shfl_xor(mx, 32, 64));
                float s = 0.f;
#pragma unroll
                for (int mt2 = 0; mt2 < 2; ++mt2)
#pragma unroll
                    for (int rr = 0; rr < 4; ++rr) {
                        float e = __expf(st[mt2][nt][rr] - mx); st[mt2][nt][rr] = e; s += e;
                    }
                s += __shfl_xor(s, 16, 64);
                s += __shfl_xor(s, 32, 64);
                pmax[nt] = mx; psum[nt] = s;
            }
            float2* smp = (float2*)(smem + SMP_OFF);        // [128 wq][4 mi]
            if (q == 0) {
#pragma unroll
                for (int nt = 0; nt < 2; ++nt)
                    smp[(w0 + nt * 16 + a) * 4 + mi] = make_float2(pmax[nt], psum[nt]);
            }
            lgkm_barrier();                 // partials visible; P2 reads done block-wide
            float f[2];
#pragma unroll
            for (int nt = 0; nt < 2; ++nt) {
                const int wq = w0 + nt * 16 + a;
                float2 pp0 = smp[wq * 4 + 0], pp1 = smp[wq * 4 + 1];
                float2 pp2 = smp[wq * 4 + 2], pp3 = smp[wq * 4 + 3];
                float m = fmaxf(fmaxf(pp0.x, pp1.x), fmaxf(pp2.x, pp3.x));
                float s = pp0.y * __expf(pp0.x - m) + pp1.y * __expf(pp1.x - m)
                        + pp2.y * __expf(pp2.x - m) + pp3.y * __expf(pp3.x - m);
                f[nt] = __expf(pmax[nt] - m) / s;
            }
            // Pl overlay of Qt/Kt is safe: barrier above was after all P2 reads
#pragma unroll
            for (int nt = 0; nt < 2; ++nt) {
                const int wq = w0 + nt * 16 + a;
#pragma unroll
                for (int mt2 = 0; mt2 < 2; ++mt2) {
                    uint2 pp;
                    pp.x = packbf2(st[mt2][nt][0] * f[nt], st[mt2][nt][1] * f[nt]);
                    pp.y = packbf2(st[mt2][nt][2] * f[nt], st[mt2][nt][3] * f[nt]);
                    *(uint2*)(smem + PL_OFF + wq * PL_SB + (mi * 32 + mt2 * 16 + q * 4) * 2) = pp;
                }
            }
        }

        // ---- P4: per 64-channel chunk: V = Wv.X + bv; O = V.P^T; out = g*O + x ----
#pragma unroll 1
        for (int mc = 0; mc < 4; ++mc) {
            if (mc == 0)              GATE("s_waitcnt vmcnt(0) lgkmcnt(0)");
            else if (mc < 3)          GATE("s_waitcnt vmcnt(8) lgkmcnt(0)");
            else if (r < 3)           GATE("s_waitcnt vmcnt(40) lgkmcnt(0)");
            else                      GATE("s_waitcnt vmcnt(8) lgkmcnt(0)");
            // V-GEMM
            f32x4 accV[2];
            {
                f32x4 cv;
#pragma unroll
                for (int rr = 0; rr < 4; ++rr) cv[rr] = biasl[128 + mc * 64 + mi * 16 + q * 4 + rr];
                accV[0] = cv; accV[1] = cv;
            }
#pragma unroll
            for (int kc = 0; kc < 4; ++kc) {
                const char* wvp = smem + WP_OFF + kc * 9216;
#pragma unroll
                for (int ks = 0; ks < 2; ++ks) {
                    bf16x8 av = *(const bf16x8*)(wvp + (mi * 16 + a) * 144 + ks * 64 + q * 16);
#pragma unroll
                    for (int nt = 0; nt < 2; ++nt) {
                        bf16x8 bx = *(const bf16x8*)(smem + XT_OFF + (w0 + nt * 16 + a) * XT_SB + (kc * 64 + ks * 32) * 2 + q * 16);
                        accV[nt] = __builtin_amdgcn_mfma_f32_16x16x32_bf16(av, bx, accV[nt], 0, 0, 0);
                    }
                }
            }
            // write Vl[c][v]
#pragma unroll
            for (int nt = 0; nt < 2; ++nt)
#pragma unroll
                for (int rr = 0; rr < 4; ++rr)
                    *(u16*)(smem + VL_OFF + (mi * 16 + q * 4 + rr) * VL_SB + (w0 + nt * 16 + a) * 2) = bfbits(accV[nt][rr]);
            GATE("s_waitcnt lgkmcnt(0)");   // Vl ready; wv(mc) page reads done
            if (mc < 3) {                   // wv(mc+1) stage, hidden under O-GEMM
                stage36k(wv_g + (mc + 1) * 36864, smem + WP_OFF, wid, l);
                pin();
                if (mc == 2 && r < 3) {     // next row's x burst AFTER wv(mc3) stage
                    const float* xn = xbase + (h + 1) * 128;
#pragma unroll
                    for (int p = 0; p < 8; ++p)
#pragma unroll
                        for (int j = 0; j < 4; ++j)
                            xv[p * 4 + j] = xn[(p * 32 + j) * 16384];
                    pin();
                }
            } else if (r < 3) {             // next row's wqk pair0/1 (WP now dead)
                stage18k(wqk_g,         smem + WP_OFF,         wid, l);
                stage18k(wqk_g + 18432, smem + WP_OFF + 18432, wid, l);
                pin();
            }
            // O-GEMM: A=Vl[c][v], B=Pl[w][v]
            f32x4 accO[2];
            accO[0] = (f32x4){0.f, 0.f, 0.f, 0.f};
            accO[1] = (f32x4){0.f, 0.f, 0.f, 0.f};
#pragma unroll
            for (int ks = 0; ks < 4; ++ks) {
                bf16x8 av = *(const bf16x8*)(smem + VL_OFF + (mi * 16 + a) * VL_SB + ks * 64 + q * 16);
#pragma unroll
                for (int nt = 0; nt < 2; ++nt) {
                    bf16x8 bp = *(const bf16x8*)(smem + PL_OFF + (w0 + nt * 16 + a) * PL_SB + ks * 64 + q * 16);
                    accO[nt] = __builtin_amdgcn_mfma_f32_16x16x32_bf16(av, bp, accO[nt], 0, 0, 0);
                }
            }
            // epilogue: residual via 2x ds_read_b64 + unpack (was 8x ds_read_u16);
            // store order unchanged: exactly 8 scalar stores (the vmcnt-gate unit)
            uint2 xp4[2];
#pragma unroll
            for (int nt = 0; nt < 2; ++nt)
                xp4[nt] = *(const uint2*)(smem + XT_OFF + (w0 + nt * 16 + a) * XT_SB + (mc * 64 + mi * 16 + q * 4) * 2);
#pragma unroll
            for (int rr = 0; rr < 4; ++rr) {
                const int c = mc * 64 + mi * 16 + q * 4 + rr;
                float* orow = out + ((b * 256 + c) * 128 + h) * 128;
#pragma unroll
                for (int nt = 0; nt < 2; ++nt) {
                    const int w = w0 + nt * 16 + a;
                    u32 word = (rr & 2) ? xp4[nt].y : xp4[nt].x;
                    u16 xvr = (rr & 1) ? (u16)(word >> 16) : (u16)(word & 0xffff);
                    orow[w] = g * accO[nt][rr] + bf2f(xvr);
                }
            }
        }
    }
}

extern "C" void kernel_launch(void* const* d_in, const int* in_sizes, int n_in,
                              void* d_out, int out_size, void* d_ws, size_t ws_size,
                              hipStream_t stream) {
    const float* x     = (const float*)d_in[0];
    const float* wq    = (const float*)d_in[1];
    const float* bq    = (const float*)d_in[2];
    const float* wk    = (const float*)d_in[3];
    const float* bk    = (const float*)d_in[4];
    const float* wv    = (const float*)d_in[5];
    const float* bv    = (const float*)d_in[6];
    const float* gamma = (const float*)d_in[7];
    float* out = (float*)d_out;

    hipLaunchKernelGGL(prep_weights, dim3(216), dim3(256), 0, stream, wq, wk, wv, (u32*)d_ws);
    hipLaunchKernelGGL(rowattn_mfma, dim3(256), dim3(1024), 0, stream,
                       x, bq, bk, bv, gamma, (const char*)d_ws, out);
}

// Round 6
// 295.393 us; speedup vs baseline: 1.2180x; 1.2180x over previous
//
#include <hip/hip_runtime.h>
#include <hip/hip_bf16.h>

// RowAttention, MFMA version (bf16 MFMA, fp32 acc). Inputs fp32, output fp32.
// v7 = v3 block structure (grid=1024, ONE (b,h) row per block; x loaded at
//      entry, consumed immediately in P0 -> short live range, no spill;
//      v4/v5/v6 kept xv[32] live across P1..P4 and spilled ~134MB/dispatch
//      to scratch regardless of launch_bounds)
//    + v4's direct-pack P0 (lane=w coalesced loads, in-register pack, one
//      ds_write_b64 per c-group; no fp32 scratch, 1 barrier)
//    + v5's global_load_lds weight staging with counted-vmcnt gates.
// block=1024 (16 waves, 4/SIMD), 1 block/CU (LDS 160 KB). Wave grid 4x4:
// mi=wid>>2 owns a 16-row m-slice, nj=wid&3 owns a 32-wide w-window.
//
// Gate discipline (per-wave, in-order VMEM retirement; issue order pinned
// with sched_barrier(0)). x is fully consumed in P0 => per-wave vmcnt==0
// entering P1. Thereafter:
//   P1 kc2:  vmcnt(2)  [newer: pair3 stage (2 instr)]
//   P1 kc3:  vmcnt(0)
//   mc0-top: vmcnt(0)  [wv(mc0) staged at P2-top, nothing newer]
//   mc1..3:  vmcnt(8)  [newer: 8 epilogue stores of prev mc]
//   Vl-ready gates: lgkmcnt(0) only.
//
// LDS map (bytes):
//   [0,     67584)  Xt  [128 w][264 c] bf16                       (whole row)
//   [67584,104448)  Qt[128][72]+Kt[128][72] bf16 -> Pl [128][136] bf16 (P3+)
//   [104448,141312) W pages: P1 = 2x18432 slots; P4 = 36864 per-mc wv chunk
//   [141312,158720) Vl  [64 c][136 v] bf16  (first 4 KB = softmax partials)
//   [158720,160256) biases fp32: bq[64] bk[64] bv[256]

typedef short bf16x8 __attribute__((ext_vector_type(8)));
typedef float f32x4 __attribute__((ext_vector_type(4)));
using u32 = unsigned int;
using u16 = unsigned short;

#define XT_OFF   0
#define XT_SB    528
#define QT_OFF   67584
#define KT_OFF   86016
#define QK_SB    144
#define PL_OFF   67584
#define PL_SB    272
#define WP_OFF   104448
#define VL_OFF   141312
#define VL_SB    272
#define SMP_OFF  141312
#define BIAS_OFF 158720
#define LDS_TOTAL 160256

// workspace: wqk_p [4 kc][2 sel(wq,wk)][64][72] bf16 (73728 B) then
//            wv_p  [4 mc][4 kc][64][72] bf16 (147456 B)
#define WS_WQK   0
#define WS_WV    73728

__device__ __forceinline__ u16 bfbits(float f) {
    __hip_bfloat16 h = __float2bfloat16(f);
    u16 u; __builtin_memcpy(&u, &h, 2); return u;
}
__device__ __forceinline__ u32 packbf2(float a, float b) {
    return (u32)bfbits(a) | ((u32)bfbits(b) << 16);
}
__device__ __forceinline__ float bf2f(u16 u) {
    union { u32 i; float f; } v; v.i = ((u32)u) << 16; return v.f;
}

// async global->LDS 16B copy; LDS dest is wave-uniform base + lane*16.
__device__ __forceinline__ void gl2lds16(const char* g, const char* l) {
    __builtin_amdgcn_global_load_lds(
        (const __attribute__((address_space(1))) void*)(unsigned long long)g,
        (__attribute__((address_space(3))) void*)(u32)(unsigned long long)l,
        16, 0, 0);
}
// stage 18432 B over 16 waves: exactly 2 vm instrs per wave (2nd lane-masked)
__device__ __forceinline__ void stage18k(const char* g, const char* lds, int w, int l) {
    gl2lds16(g + w * 1024 + l * 16, lds + w * 1024);
    if (l < 8) gl2lds16(g + 16384 + w * 128 + l * 16, lds + 16384 + w * 128);
}
// stage 36864 B over 16 waves: exactly 3 vm instrs per wave
__device__ __forceinline__ void stage36k(const char* g, const char* lds, int w, int l) {
    gl2lds16(g + w * 1024 + l * 16,         lds + w * 1024);
    gl2lds16(g + 16384 + w * 1024 + l * 16, lds + 16384 + w * 1024);
    if (l < 16) gl2lds16(g + 32768 + w * 256 + l * 16, lds + 32768 + w * 256);
}

#define GATE(WAITSTR) do { \
    __builtin_amdgcn_sched_barrier(0); \
    asm volatile(WAITSTR "\n\ts_barrier" ::: "memory"); \
    __builtin_amdgcn_sched_barrier(0); \
} while (0)

// plain barrier: per-wave lgkm already drained by operand consumption
__device__ __forceinline__ void hard_barrier() {
    __builtin_amdgcn_sched_barrier(0);
    asm volatile("s_barrier" ::: "memory");
    __builtin_amdgcn_sched_barrier(0);
}
__device__ __forceinline__ void lgkm_barrier() {
    __builtin_amdgcn_sched_barrier(0);
    asm volatile("s_waitcnt lgkmcnt(0)\n\ts_barrier" ::: "memory");
    __builtin_amdgcn_sched_barrier(0);
}
__device__ __forceinline__ void pin() { __builtin_amdgcn_sched_barrier(0); }

__global__ void prep_weights(const float* __restrict__ wq, const float* __restrict__ wk,
                             const float* __restrict__ wv, u32* __restrict__ ws) {
    int i = blockIdx.x * 256 + threadIdx.x;        // u32 word index, 55296 total
    if (i >= 55296) return;
    u32 v = 0;
    if (i < 18432) {                               // wqk_p: 8 chunk-halves of 2304 words
        int c = i / 2304, rem = i % 2304;
        int row = rem / 36, iw = rem % 36;
        int kc = c >> 1;
        const float* m = (c & 1) ? wk : wq;
        if (iw < 32) {
            int col = kc * 64 + iw * 2;
            v = packbf2(m[row * 256 + col], m[row * 256 + col + 1]);
        }
    } else {                                       // wv_p: 16 chunks of 2304 words
        int j = i - 18432;
        int c = j / 2304, rem = j % 2304;
        int row = rem / 36, iw = rem % 36;
        int mc = c >> 2, kc = c & 3;
        if (iw < 32) {
            int col = kc * 64 + iw * 2;
            v = packbf2(wv[(mc * 64 + row) * 256 + col], wv[(mc * 64 + row) * 256 + col + 1]);
        }
    }
    ws[i] = v;
}

__global__ __launch_bounds__(1024, 1) void rowattn_mfma(
    const float* __restrict__ x,      // (8,256,128,128)
    const float* __restrict__ bq,     // (64,)
    const float* __restrict__ bk,     // (64,)
    const float* __restrict__ bv,     // (256,)
    const float* __restrict__ gamma,  // (1,)
    const char* __restrict__ wsp,     // prep_weights output (bf16, padded chunks)
    float* __restrict__ out)          // (8,256,128,128)
{
    __shared__ __align__(16) char smem[LDS_TOTAL];
    const int t  = threadIdx.x;                             // 0..1023
    const int l  = t & 63;
    const int a  = l & 15;                                  // MFMA col-within-tile
    const int q  = l >> 4;                                  // MFMA quad
    const int wid = __builtin_amdgcn_readfirstlane(t >> 6); // 0..15
    const int mi = wid >> 2;                                // m-slice 0..3
    const int nj = wid & 3;                                 // n-window 0..3
    const int w0 = nj * 32;                                 // w-window base

    const int bh = blockIdx.x;                              // 0..1023
    const int b  = bh >> 7;
    const int h  = bh & 127;

    const char* wqk_g = wsp + WS_WQK;
    const char* wv_g  = wsp + WS_WV;
    const float g = gamma[0];

    // ---- entry: pair0/1 DMA first (oldest), then biases, then x burst ----
    stage18k(wqk_g,         smem + WP_OFF,         wid, l);
    stage18k(wqk_g + 18432, smem + WP_OFF + 18432, wid, l);
    pin();

    float* biasl = (float*)(smem + BIAS_OFF);
    if (t < 384) {
        float v;
        if (t < 64) v = bq[t];
        else if (t < 128) v = bk[t - 64];
        else v = bv[t - 128];
        biasl[t] = v;
    }
    pin();

    // x burst: lane=w (coalesced per instr), 4 c's per thread, 8 c-groups.
    // Consumed IMMEDIATELY in P0 -> short live range -> no spill (v3-proven).
    const int xw  = ((wid & 8) << 3) + l;                   // 0..127
    const int xcb = (wid & 7) * 4;                          // c base 0..28
    const float* xp = x + (size_t)(b * 256 + xcb) * 16384 + (size_t)h * 128 + xw;
    float xv[32];
#pragma unroll
    for (int p = 0; p < 8; ++p)
#pragma unroll
        for (int j = 0; j < 4; ++j)
            xv[p * 4 + j] = xp[(p * 32 + j) * 16384];
    pin();

    // ---- P0: pack xv -> Xt[w][c] (consuming x drains vmcnt to 0) ----
#pragma unroll
    for (int p = 0; p < 8; ++p) {
        uint2 pk;
        pk.x = packbf2(xv[p * 4 + 0], xv[p * 4 + 1]);
        pk.y = packbf2(xv[p * 4 + 2], xv[p * 4 + 3]);
        *(uint2*)(smem + XT_OFF + xw * XT_SB + (xcb + p * 32) * 2) = pk;
    }
    // Xt + biases visible; pair0/1 DMA retired (older than consumed x loads)
    GATE("s_waitcnt lgkmcnt(0)");

    // ---- P1: Q,K projections -> Qt[wq][o], Kt[wk][o] ----
    {
        f32x4 accQ[2], accK[2];
        {
            f32x4 cq, ck;
#pragma unroll
            for (int rr = 0; rr < 4; ++rr) {
                cq[rr] = biasl[mi * 16 + q * 4 + rr];
                ck[rr] = biasl[64 + mi * 16 + q * 4 + rr];
            }
            accQ[0] = cq; accQ[1] = cq; accK[0] = ck; accK[1] = ck;
        }
#pragma unroll
        for (int kc = 0; kc < 4; ++kc) {
            if (kc == 2) GATE("s_waitcnt vmcnt(2)");   // pair2 done (pair3's 2 fly)
            if (kc == 3) GATE("s_waitcnt vmcnt(0)");   // pair3 done
            const char* wqp = smem + WP_OFF + (kc & 1) * 18432;
            const char* wkp = wqp + 9216;
#pragma unroll
            for (int ks = 0; ks < 2; ++ks) {
                bf16x8 aq = *(const bf16x8*)(wqp + (mi * 16 + a) * 144 + ks * 64 + q * 16);
                bf16x8 ak = *(const bf16x8*)(wkp + (mi * 16 + a) * 144 + ks * 64 + q * 16);
#pragma unroll
                for (int nt = 0; nt < 2; ++nt) {
                    bf16x8 bx = *(const bf16x8*)(smem + XT_OFF + (w0 + nt * 16 + a) * XT_SB + (kc * 64 + ks * 32) * 2 + q * 16);
                    accQ[nt] = __builtin_amdgcn_mfma_f32_16x16x32_bf16(aq, bx, accQ[nt], 0, 0, 0);
                    accK[nt] = __builtin_amdgcn_mfma_f32_16x16x32_bf16(ak, bx, accK[nt], 0, 0, 0);
                }
            }
            if (kc == 0) { hard_barrier(); stage18k(wqk_g + 2 * 18432, smem + WP_OFF,         wid, l); pin(); }
            if (kc == 1) { hard_barrier(); stage18k(wqk_g + 3 * 18432, smem + WP_OFF + 18432, wid, l); pin(); }
        }
        // write Qt/Kt transposed: C[m=o][n=w] -> Qt[w][o]
#pragma unroll
        for (int nt = 0; nt < 2; ++nt) {
            const int wrow = w0 + nt * 16 + a;
            uint2 pq; pq.x = packbf2(accQ[nt][0], accQ[nt][1]); pq.y = packbf2(accQ[nt][2], accQ[nt][3]);
            *(uint2*)(smem + QT_OFF + wrow * QK_SB + (mi * 16 + q * 4) * 2) = pq;
            uint2 pk; pk.x = packbf2(accK[nt][0], accK[nt][1]); pk.y = packbf2(accK[nt][2], accK[nt][3]);
            *(uint2*)(smem + KT_OFF + wrow * QK_SB + (mi * 16 + q * 4) * 2) = pk;
        }
    }
    GATE("s_waitcnt lgkmcnt(0)");       // Qt/Kt visible; kc3 page reads done
    stage36k(wv_g, smem + WP_OFF, wid, l);  // wv mc0 (hidden under P2/P3)
    pin();

    // ---- P2: St tiles; wave (mi,nj): wk in [mi*32,+32), wq in [nj*32,+32) ----
    f32x4 st[2][2];
#pragma unroll
    for (int mt2 = 0; mt2 < 2; ++mt2)
#pragma unroll
        for (int nt = 0; nt < 2; ++nt) st[mt2][nt] = (f32x4){0.f, 0.f, 0.f, 0.f};
#pragma unroll
    for (int ks = 0; ks < 2; ++ks) {
        bf16x8 bq0 = *(const bf16x8*)(smem + QT_OFF + (w0 + a) * QK_SB + ks * 64 + q * 16);
        bf16x8 bq1 = *(const bf16x8*)(smem + QT_OFF + (w0 + 16 + a) * QK_SB + ks * 64 + q * 16);
        bf16x8 ak0 = *(const bf16x8*)(smem + KT_OFF + (mi * 32 + a) * QK_SB + ks * 64 + q * 16);
        bf16x8 ak1 = *(const bf16x8*)(smem + KT_OFF + (mi * 32 + 16 + a) * QK_SB + ks * 64 + q * 16);
        st[0][0] = __builtin_amdgcn_mfma_f32_16x16x32_bf16(ak0, bq0, st[0][0], 0, 0, 0);
        st[0][1] = __builtin_amdgcn_mfma_f32_16x16x32_bf16(ak0, bq1, st[0][1], 0, 0, 0);
        st[1][0] = __builtin_amdgcn_mfma_f32_16x16x32_bf16(ak1, bq0, st[1][0], 0, 0, 0);
        st[1][1] = __builtin_amdgcn_mfma_f32_16x16x32_bf16(ak1, bq1, st[1][1], 0, 0, 0);
    }
    // ---- P3: softmax: in-wave partial (32 wk) then 4-way mi-combine ----
    {
        float pmax[2], psum[2];
#pragma unroll
        for (int nt = 0; nt < 2; ++nt) {
            float mx = -3.0e38f;
#pragma unroll
            for (int mt2 = 0; mt2 < 2; ++mt2)
#pragma unroll
                for (int rr = 0; rr < 4; ++rr) mx = fmaxf(mx, st[mt2][nt][rr]);
            mx = fmaxf(mx, __shfl_xor(mx, 16, 64));
            mx = fmaxf(mx, __shfl_xor(mx, 32, 64));
            float s = 0.f;
#pragma unroll
            for (int mt2 = 0; mt2 < 2; ++mt2)
#pragma unroll
                for (int rr = 0; rr < 4; ++rr) {
                    float e = __expf(st[mt2][nt][rr] - mx); st[mt2][nt][rr] = e; s += e;
                }
            s += __shfl_xor(s, 16, 64);
            s += __shfl_xor(s, 32, 64);
            pmax[nt] = mx; psum[nt] = s;
        }
        float2* smp = (float2*)(smem + SMP_OFF);            // [128 wq][4 mi]
        if (q == 0) {
#pragma unroll
            for (int nt = 0; nt < 2; ++nt)
                smp[(w0 + nt * 16 + a) * 4 + mi] = make_float2(pmax[nt], psum[nt]);
        }
        lgkm_barrier();                 // partials visible; P2 reads done block-wide
        float f[2];
#pragma unroll
        for (int nt = 0; nt < 2; ++nt) {
            const int wq = w0 + nt * 16 + a;
            float2 pp0 = smp[wq * 4 + 0], pp1 = smp[wq * 4 + 1];
            float2 pp2 = smp[wq * 4 + 2], pp3 = smp[wq * 4 + 3];
            float m = fmaxf(fmaxf(pp0.x, pp1.x), fmaxf(pp2.x, pp3.x));
            float s = pp0.y * __expf(pp0.x - m) + pp1.y * __expf(pp1.x - m)
                    + pp2.y * __expf(pp2.x - m) + pp3.y * __expf(pp3.x - m);
            f[nt] = __expf(pmax[nt] - m) / s;
        }
        // Pl overlay of Qt/Kt is safe: barrier above was after all P2 reads
#pragma unroll
        for (int nt = 0; nt < 2; ++nt) {
            const int wq = w0 + nt * 16 + a;
#pragma unroll
            for (int mt2 = 0; mt2 < 2; ++mt2) {
                uint2 pp;
                pp.x = packbf2(st[mt2][nt][0] * f[nt], st[mt2][nt][1] * f[nt]);
                pp.y = packbf2(st[mt2][nt][2] * f[nt], st[mt2][nt][3] * f[nt]);
                *(uint2*)(smem + PL_OFF + wq * PL_SB + (mi * 32 + mt2 * 16 + q * 4) * 2) = pp;
            }
        }
    }

    // ---- P4: per 64-channel chunk: V = Wv.X + bv; O = V.P^T; out = g*O + x ----
#pragma unroll 1
    for (int mc = 0; mc < 4; ++mc) {
        if (mc == 0) GATE("s_waitcnt vmcnt(0) lgkmcnt(0)");   // wv0 + Pl ready
        else         GATE("s_waitcnt vmcnt(8) lgkmcnt(0)");   // wv(mc) ready (8 stores newer)
        // V-GEMM
        f32x4 accV[2];
        {
            f32x4 cv;
#pragma unroll
            for (int rr = 0; rr < 4; ++rr) cv[rr] = biasl[128 + mc * 64 + mi * 16 + q * 4 + rr];
            accV[0] = cv; accV[1] = cv;
        }
#pragma unroll
        for (int kc = 0; kc < 4; ++kc) {
            const char* wvp = smem + WP_OFF + kc * 9216;
#pragma unroll
            for (int ks = 0; ks < 2; ++ks) {
                bf16x8 av = *(const bf16x8*)(wvp + (mi * 16 + a) * 144 + ks * 64 + q * 16);
#pragma unroll
                for (int nt = 0; nt < 2; ++nt) {
                    bf16x8 bx = *(const bf16x8*)(smem + XT_OFF + (w0 + nt * 16 + a) * XT_SB + (kc * 64 + ks * 32) * 2 + q * 16);
                    accV[nt] = __builtin_amdgcn_mfma_f32_16x16x32_bf16(av, bx, accV[nt], 0, 0, 0);
                }
            }
        }
        // write Vl[c][v]
#pragma unroll
        for (int nt = 0; nt < 2; ++nt)
#pragma unroll
            for (int rr = 0; rr < 4; ++rr)
                *(u16*)(smem + VL_OFF + (mi * 16 + q * 4 + rr) * VL_SB + (w0 + nt * 16 + a) * 2) = bfbits(accV[nt][rr]);
        GATE("s_waitcnt lgkmcnt(0)");   // Vl ready; wv(mc) page reads done
        if (mc < 3) {                   // wv(mc+1) stage, hidden under O-GEMM
            stage36k(wv_g + (mc + 1) * 36864, smem + WP_OFF, wid, l);
            pin();
        }
        // O-GEMM: A=Vl[c][v], B=Pl[w][v]
        f32x4 accO[2];
        accO[0] = (f32x4){0.f, 0.f, 0.f, 0.f};
        accO[1] = (f32x4){0.f, 0.f, 0.f, 0.f};
#pragma unroll
        for (int ks = 0; ks < 4; ++ks) {
            bf16x8 av = *(const bf16x8*)(smem + VL_OFF + (mi * 16 + a) * VL_SB + ks * 64 + q * 16);
#pragma unroll
            for (int nt = 0; nt < 2; ++nt) {
                bf16x8 bp = *(const bf16x8*)(smem + PL_OFF + (w0 + nt * 16 + a) * PL_SB + ks * 64 + q * 16);
                accO[nt] = __builtin_amdgcn_mfma_f32_16x16x32_bf16(av, bp, accO[nt], 0, 0, 0);
            }
        }
        // epilogue: residual via 2x ds_read_b64 + unpack; exactly 8 stores
        uint2 xp4[2];
#pragma unroll
        for (int nt = 0; nt < 2; ++nt)
            xp4[nt] = *(const uint2*)(smem + XT_OFF + (w0 + nt * 16 + a) * XT_SB + (mc * 64 + mi * 16 + q * 4) * 2);
#pragma unroll
        for (int rr = 0; rr < 4; ++rr) {
            const int c = mc * 64 + mi * 16 + q * 4 + rr;
            float* orow = out + ((b * 256 + c) * 128 + h) * 128;
#pragma unroll
            for (int nt = 0; nt < 2; ++nt) {
                const int w = w0 + nt * 16 + a;
                u32 word = (rr & 2) ? xp4[nt].y : xp4[nt].x;
                u16 xvr = (rr & 1) ? (u16)(word >> 16) : (u16)(word & 0xffff);
                orow[w] = g * accO[nt][rr] + bf2f(xvr);
            }
        }
    }
}

extern "C" void kernel_launch(void* const* d_in, const int* in_sizes, int n_in,
                              void* d_out, int out_size, void* d_ws, size_t ws_size,
                              hipStream_t stream) {
    const float* x     = (const float*)d_in[0];
    const float* wq    = (const float*)d_in[1];
    const float* bq    = (const float*)d_in[2];
    const float* wk    = (const float*)d_in[3];
    const float* bk    = (const float*)d_in[4];
    const float* wv    = (const float*)d_in[5];
    const float* bv    = (const float*)d_in[6];
    const float* gamma = (const float*)d_in[7];
    float* out = (float*)d_out;

    hipLaunchKernelGGL(prep_weights, dim3(216), dim3(256), 0, stream, wq, wk, wv, (u32*)d_ws);
    hipLaunchKernelGGL(rowattn_mfma, dim3(1024), dim3(1024), 0, stream,
                       x, bq, bk, bv, gamma, (const char*)d_ws, out);
}